// Round 10
// baseline (125.766 us; speedup 1.0000x reference)
//
#include <hip/hip_runtime.h>
#include <hip/hip_bf16.h>

// NT-Xent loss, N=4096, D=256, fp32 inputs, fp32 scalar output.
// loss = mean_i [ log( sum_{j != i} exp(2*cos(zn_i, zn_j)) ) - 2*cos(zn_i, zn_pair(i)) ]
//
// v10: symmetric circulant gram at r0's OCCUPANCY shape.
// r0-r9 synthesis: gram stuck at 40-48us in every variant; the one config that
// hit 793 TF (r0/r1 full gram) had 4 waves/SIMD (512thr x 2blk/CU); all
// rewrites ran 2/SIMD and paid ~25us of unhidden latency. v10 = symmetric
// work + 512 thr (8 waves: 4 row-groups x 2 col-halves) + 128-row tiles +
// grid 512 (2 blk/CU -> 16 waves/CU) + the r4-proven 0-conflict swizzle +
// counted vmcnt (20/6/2, atomics counted) + launch_bounds(512,4) caps VGPR
// at 128 (est ~100: a=64, acc=16 -- smaller than r0's measured 108).

#define NROWS 8192
#define NHALF 4096
#define DDIM  256
#define GBLK  512   // 64 I-tiles x 8 chunks

typedef __bf16 bf16;
typedef __bf16 bf16x4 __attribute__((ext_vector_type(4)));
typedef __bf16 bf16x8 __attribute__((ext_vector_type(8)));
typedef float  f32x4  __attribute__((ext_vector_type(4)));

__constant__ const float kTwoLog2e = 2.8853900817779268f;  // 2*log2(e): exp(2x)=exp2(kTwoLog2e*x)
__constant__ const float kLn2      = 0.6931471805599453f;

__device__ __forceinline__ const float* zrow(const float* z1, const float* z2, int r) {
  return (r < NHALF) ? (z1 + (size_t)r * DDIM) : (z2 + (size_t)(r - NHALF) * DDIM);
}

typedef const __attribute__((address_space(1))) unsigned int* as1_u32p;
typedef __attribute__((address_space(3))) unsigned int* as3_u32p;

__device__ __forceinline__ void load_lds16(const void* g, void* l) {
  __builtin_amdgcn_global_load_lds((as1_u32p)g, (as3_u32p)l, 16, 0, 0);
}

// ---------------- k1: normalize ----------------
__global__ void k_normalize(const float* __restrict__ z1, const float* __restrict__ z2,
                            bf16* __restrict__ zn, float* __restrict__ invn,
                            float* __restrict__ rowsum, float* __restrict__ out) {
  const int wave = threadIdx.x >> 6, lane = threadIdx.x & 63;
  const int row = blockIdx.x * 4 + wave;
  f32x4 v = *(const f32x4*)(zrow(z1, z2, row) + lane * 4);
  float ss = v.x * v.x + v.y * v.y + v.z * v.z + v.w * v.w;
#pragma unroll
  for (int off = 1; off < 64; off <<= 1) ss += __shfl_xor(ss, off);
  const float inv = 1.0f / fmaxf(sqrtf(ss), 1e-8f);
  bf16x4 o;
  o.x = (bf16)(v.x * inv); o.y = (bf16)(v.y * inv);
  o.z = (bf16)(v.z * inv); o.w = (bf16)(v.w * inv);
  *(bf16x4*)(zn + (size_t)row * DDIM + lane * 4) = o;
  if (lane == 0) { invn[row] = inv; rowsum[row] = 0.0f; }
  if (blockIdx.x == 0 && threadIdx.x == 0) out[0] = 0.0f;
}

// ---------------- k2: circulant symmetric Gram, 4 waves/SIMD ----------------
// Block (I, chunk): I in [0,64) row-tile of 128; chunk in [0,8) covers d in
// {4c..4c+3} (+d=32 for chunk7 & I<32). J=(I+d)&63; n = 8 (or 10) 64-col
// LDS-iters. Coverage: delta in [1,31] once from the I side, delta=32 once via
// I<32, delta>=33 from the J side; d=0 diag row-sums only (col atomic adds
// 0.0f to keep per-wave VMEM count uniform -> waits stay sound).
// Waves: rg = wave>>1 owns rows R0 = I*128+rg*32 (s=2 x 16); ch = wave&1 owns
// staged cols [ch*32, ch*32+32) (cs=2 x 16). 16 ds_read + 32 MFMA per wave-iter.
// Pipeline: 2x32KB dbuf, DMA-swizzled source (0 bank conflicts, r4-measured).
// Per-wave VMEM stream: D0(4) A(16) D1(4) | iter t: wait; {2 col atomics};
// barrier; D(t+2)(4). Waits: t=0: after D0 remain A+D1=20 -> vmcnt(20);
// 1<=t<=n-2: after D(t) remain At(t-1)+D(t+1)=6 -> vmcnt(6);
// t=n-1: after D(n-1) remain At(n-2)=2 -> vmcnt(2). In-order retirement (m135).
__global__ __launch_bounds__(512, 4) void k_gram(const bf16* __restrict__ zn,
                                                 float* __restrict__ rowsum) {
  __shared__ __align__(16) unsigned char ldsb[2][64 * 512];  // 64KB -> 2 blk/CU
  const int tid  = threadIdx.x;
  const int wave = tid >> 6, lane = tid & 63;
  const int quad = lane >> 4, l15 = lane & 15;
  const int rg = wave >> 1, ch = wave & 1;

  const int I      = blockIdx.x >> 3;   // [0,64)
  const int chunk  = blockIdx.x & 7;    // [0,8)
  const int base_d = chunk * 4;
  const int n      = (chunk == 7 && I < 32) ? 10 : 8;  // 64-col LDS-iters
  const int R0     = I * 128 + rg * 32;

  auto cbase = [&](int t) -> int {
    const int d = base_d + (t >> 1);
    const int J = (I + d) & 63;
    return J * 128 + (t & 1) * 64;
  };
  auto issue_dma = [&](int t, int b) {
    const unsigned char* s = (const unsigned char*)(zn + (size_t)cbase(t) * DDIM);
#pragma unroll
    for (int j = 0; j < 4; ++j) {
      const int p = (wave * 4 + j) * 64 + lane;  // 16B-chunk position 0..2047
      const int r = p >> 5;                      // staged col-row 0..63
      const int q = (p & 31) ^ (r & 15);         // swizzle inverse on SOURCE
      load_lds16(s + r * 512 + q * 16, &ldsb[b][(wave * 4 + j) * 1024]);
    }
  };

  // pinned VMEM issue order: [D0 x4] [A x16] [D1 x4]
  issue_dma(0, 0);
  __builtin_amdgcn_sched_barrier(0);

  bf16x8 a[2][8];
#pragma unroll
  for (int s = 0; s < 2; ++s) {
    const bf16x8* ap = (const bf16x8*)(zn + (size_t)(R0 + s * 16 + l15) * DDIM);
#pragma unroll
    for (int kk = 0; kk < 8; ++kk) a[s][kk] = ap[kk * 4 + quad];
  }
  __builtin_amdgcn_sched_barrier(0);

  issue_dma(1, 1);
  __builtin_amdgcn_sched_barrier(0);

  float sum[2][4] = {{0.f, 0.f, 0.f, 0.f}, {0.f, 0.f, 0.f, 0.f}};
  const f32x4 zero4 = {0.f, 0.f, 0.f, 0.f};

  for (int t = 0; t < n; ++t) {
    if (t == 0)          asm volatile("s_waitcnt vmcnt(20)" ::: "memory");
    else if (t == n - 1) asm volatile("s_waitcnt vmcnt(2)" ::: "memory");
    else                 asm volatile("s_waitcnt vmcnt(6)" ::: "memory");
    __builtin_amdgcn_s_barrier();        // all waves' DMA for tile t complete
    __builtin_amdgcn_sched_barrier(0);   // no ds_read hoisting above barrier

    const unsigned char* bp = ldsb[t & 1];

    f32x4 acc[2][2];
#pragma unroll
    for (int s = 0; s < 2; ++s) { acc[s][0] = zero4; acc[s][1] = zero4; }

    __builtin_amdgcn_s_setprio(1);
#pragma unroll
    for (int kk = 0; kk < 8; ++kk) {
      bf16x8 b[2];
#pragma unroll
      for (int cs = 0; cs < 2; ++cs) {
        const int rb = ch * 32 + cs * 16 + l15;      // staged col-row 0..63
        const int sl = (kk * 4 + quad) ^ (rb & 15);  // swizzled chunk slot
        b[cs] = *(const bf16x8*)(bp + rb * 512 + sl * 16);
      }
#pragma unroll
      for (int s = 0; s < 2; ++s)
#pragma unroll
        for (int cs = 0; cs < 2; ++cs)
          acc[s][cs] =
              __builtin_amdgcn_mfma_f32_16x16x32_bf16(a[s][kk], b[cs], acc[s][cs], 0, 0, 0);
    }
    __builtin_amdgcn_s_setprio(0);

    // exp + row accumulation + uniform col atomics (diag adds 0.0f)
    const bool dg = (chunk == 0 && t < 2);  // d==0 diagonal tile
    const int cb = cbase(t);
#pragma unroll
    for (int cs = 0; cs < 2; ++cs) {
      float c = 0.f;
#pragma unroll
      for (int s = 0; s < 2; ++s)
#pragma unroll
        for (int r = 0; r < 4; ++r) {
          const float e = __builtin_amdgcn_exp2f(acc[s][cs][r] * kTwoLog2e);
          sum[s][r] += e;
          c += e;
        }
      // c holds this wave's 8 rows (quad's rows) for col cs*16+l15 of its half;
      // xor16/32 sums across the 4 quads -> all 32 rows of this row-group.
      c += __shfl_xor(c, 16); c += __shfl_xor(c, 32);
      if (quad == 0) atomicAdd(&rowsum[cb + ch * 32 + cs * 16 + l15], dg ? 0.0f : c);
    }

    __builtin_amdgcn_s_barrier();        // all waves done READING tile t
    __builtin_amdgcn_sched_barrier(0);
    if (t + 2 < n) {
      issue_dma(t + 2, t & 1);           // overwrite just-freed buffer
      __builtin_amdgcn_sched_barrier(0);
    }
  }

  // row-sums (wave-exclusive rows): C/D layout (m89): row=quad*4+r, col=l15
#pragma unroll
  for (int s = 0; s < 2; ++s)
#pragma unroll
    for (int r = 0; r < 4; ++r) {
      float v = sum[s][r];
      v += __shfl_xor(v, 1); v += __shfl_xor(v, 2);
      v += __shfl_xor(v, 4); v += __shfl_xor(v, 8);
      if (l15 == 0) atomicAdd(&rowsum[R0 + s * 16 + quad * 4 + r], v);
    }
}

// ---------------- k3: per-row contribution + fused reduce ----------------
__global__ void k_finalize(const float* __restrict__ z1, const float* __restrict__ z2,
                           const bf16* __restrict__ zn, const float* __restrict__ invn,
                           const float* __restrict__ rowsum, float* __restrict__ out) {
  const int wave = threadIdx.x >> 6, lane = threadIdx.x & 63;
  const int row = blockIdx.x * 4 + wave;
  const int pr = (row < NHALF) ? row + NHALF : row - NHALF;

  f32x4 a4 = *(const f32x4*)(zrow(z1, z2, row) + lane * 4);
  f32x4 b4 = *(const f32x4*)(zrow(z1, z2, pr) + lane * 4);
  bf16x4 nb = *(const bf16x4*)(zn + (size_t)row * DDIM + lane * 4);

  float pd = a4.x * b4.x + a4.y * b4.y + a4.z * b4.z + a4.w * b4.w;
  float f0 = (float)nb.x, f1 = (float)nb.y, f2 = (float)nb.z, f3 = (float)nb.w;
  float nd = f0 * f0 + f1 * f1 + f2 * f2 + f3 * f3;
#pragma unroll
  for (int off = 1; off < 64; off <<= 1) {
    pd += __shfl_xor(pd, off);
    nd += __shfl_xor(nd, off);
  }
  __shared__ float wsum[4];
  if (lane == 0) {
    const float p = 2.0f * pd * invn[row] * invn[pr];              // exact fp32 pair sim
    const float dexp = __builtin_amdgcn_exp2f(kTwoLog2e * nd);     // Gram's diagonal term
    const float lse = __builtin_amdgcn_logf(rowsum[row] - dexp) * kLn2;
    wsum[wave] = lse - p;
  }
  __syncthreads();
  if (threadIdx.x == 0)
    atomicAdd(out, (wsum[0] + wsum[1] + wsum[2] + wsum[3]) * (1.0f / (float)NROWS));
}

extern "C" void kernel_launch(void* const* d_in, const int* in_sizes, int n_in,
                              void* d_out, int out_size, void* d_ws, size_t ws_size,
                              hipStream_t stream) {
  const float* z1 = (const float*)d_in[0];
  const float* z2 = (const float*)d_in[1];
  unsigned char* ws = (unsigned char*)d_ws;

  // ws layout: zn bf16 [8192*256] (4 MB) | invn f32[8192] | rowsum f32[8192]
  bf16* zn = (bf16*)ws;
  float* invn = (float*)(ws + (size_t)NROWS * DDIM * sizeof(bf16));
  float* rowsum = invn + NROWS;
  float* out = (float*)d_out;

  hipLaunchKernelGGL(k_normalize, dim3(NROWS / 4), dim3(256), 0, stream, z1, z2, zn, invn, rowsum,
                     out);
  hipLaunchKernelGGL(k_gram, dim3(GBLK), dim3(512), 0, stream, zn, rowsum);
  hipLaunchKernelGGL(k_finalize, dim3(NROWS / 4), dim3(256), 0, stream, z1, z2, zn, invn, rowsum,
                     out);
}